// Round 5
// baseline (355.137 us; speedup 1.0000x reference)
//
#include <hip/hip_runtime.h>

typedef int v4i  __attribute__((ext_vector_type(4)));
typedef int v16i __attribute__((ext_vector_type(16)));

__device__ __forceinline__ int pack4i(int a, int b, int c, int d) {
  return (a & 255) | ((b & 255) << 8) | ((c & 255) << 16) | ((d & 255) << 24);
}
// SWAR per-byte add (mod-256 per lane-byte)
__device__ __forceinline__ int badd4(int a, int b) {
  return ((a & 0x7f7f7f7f) + (b & 0x7f7f7f7f)) ^ ((a ^ b) & 0x80808080);
}

__device__ __forceinline__ void async_ld16(const void* g, void* l) {
  __builtin_amdgcn_global_load_lds(
      (const __attribute__((address_space(1))) void*)g,
      (__attribute__((address_space(3))) void*)l, 16, 0, 0);
}

#define MFMA_I8(a, b, c) __builtin_amdgcn_mfma_i32_32x32x32_i8(a, b, c, 0, 0, 0)
// Counted waits + raw barrier: __syncthreads() would drain vmcnt to 0 and
// kill the pipeline (guide §5). BARX orders ds ops (lgkmcnt) then syncs.
#define WAITV(N) asm volatile("s_waitcnt vmcnt(" #N ")" ::: "memory")
#define BARX do { asm volatile("s_waitcnt lgkmcnt(0)" ::: "memory"); \
                  __builtin_amdgcn_s_barrier(); } while (0)

// ---------------------------------------------------------------------------
// Pack (W + E) -> int8, transposed Bt[n][k] (row stride K bytes).
// Tile: 64 n x 256 k per block, 256 threads. Zero-pads n >= N rows.
// ---------------------------------------------------------------------------
__device__ void pack_tile(const int* __restrict__ W, const int* __restrict__ E,
                          char* __restrict__ Bt, int K, int N,
                          int nx, int ky, char* lin) {
  const int t = threadIdx.x;
  const int n0 = nx * 64, k0 = ky * 256;
  {
    const int c  = t & 15;          // column group: 4 ints = 16 B
    const int kq = t >> 4;          // 0..15
    const int ng = n0 + c * 4;
    #pragma unroll 4
    for (int s = 0; s < 16; ++s) {
      const int k = s * 16 + kq;
      const long grow = (long)(k0 + k) * N;
      int a0, a1, a2, a3;
      if (ng + 3 < N) {
        int4 wv = *(const int4*)(W + grow + ng);
        int4 ev = *(const int4*)(E + grow + ng);
        a0 = wv.x + ev.x; a1 = wv.y + ev.y; a2 = wv.z + ev.z; a3 = wv.w + ev.w;
      } else {
        a0 = (ng + 0 < N) ? W[grow + ng + 0] + E[grow + ng + 0] : 0;
        a1 = (ng + 1 < N) ? W[grow + ng + 1] + E[grow + ng + 1] : 0;
        a2 = (ng + 2 < N) ? W[grow + ng + 2] + E[grow + ng + 2] : 0;
        a3 = (ng + 3 < N) ? W[grow + ng + 3] + E[grow + ng + 3] : 0;
      }
      *(int*)(lin + k * 68 + c * 4) = pack4i(a0, a1, a2, a3);
    }
  }
  __syncthreads();
  {
    const int n = t & 63, kq = t >> 6;
    char* dst = Bt + (long)(n0 + n) * K + k0 + (kq << 6);
    int outv[16];
    #pragma unroll
    for (int g = 0; g < 16; ++g) {
      const int k = (kq << 6) + (g << 2);
      outv[g] = pack4i(lin[(k + 0) * 68 + n], lin[(k + 1) * 68 + n],
                       lin[(k + 2) * 68 + n], lin[(k + 3) * 68 + n]);
    }
    #pragma unroll
    for (int g = 0; g < 4; ++g)
      *(int4*)(dst + (g << 4)) =
          make_int4(outv[g * 4], outv[g * 4 + 1], outv[g * 4 + 2], outv[g * 4 + 3]);
  }
}

__global__ __launch_bounds__(256) void pack_weights_kernel(
    const int* W1, const int* E1, char* Bt1,
    const int* W2, const int* E2, char* Bt2,
    const int* W3, const int* E3, char* Bt3,
    const int* b1, const int* eb1, int* bs1,
    const int* b2, const int* eb2, int* bs2,
    const int* b3, const int* eb3, int* bs3) {
  __shared__ __align__(16) char smem[17408];
  const int bid = blockIdx.x;
  if (bid < 192) {
    pack_tile(W1, E1, Bt1, 3072, 1024, bid % 16, bid / 16, smem);
  } else if (bid < 256) {
    const int l = bid - 192;
    pack_tile(W2, E2, Bt2, 1024, 1024, l % 16, l / 16, smem);
  } else if (bid < 264) {
    const int l = bid - 256;
    pack_tile(W3, E3, Bt3, 1024, 100, l & 1, l >> 1, smem);
  } else {
    const int t = threadIdx.x;
    for (int i = t; i < 1024; i += 256) {
      bs1[i] = b1[i] + eb1[i];
      bs2[i] = b2[i] + eb2[i];
    }
    for (int i = t; i < 128; i += 256)
      bs3[i] = (i < 100) ? (b3[i] + eb3[i]) : 0;
  }
}

// ---------------------------------------------------------------------------
// R5 gemm1: 128x128 tile, BK=64, 256 thr (4 waves, 2x2 x 64x64), 3-stage LDS
// pipeline with COUNTED vmcnt (T3+T4). R4 proved source-level reg prefetch is
// discarded by hipcc (VGPR=88, MfmaUtil 8.9%): the pipeline must be explicit.
//  - B staged via global_load_lds issued 2 K-steps ahead; never drained to 0
//    in the loop (vmcnt(10) leaves the newest step's 10 ops in flight).
//  - A (int32 X) loaded into one of two NAMED reg sets 2 steps ahead,
//    packed+ds_written 1 step ahead (after vmcnt confirms landing).
//  - LDS rows are linear 64 B (DMA needs linear dest); bank conflicts fixed
//    by the rule-#21 pattern: 16B-chunk swizzle c^=row&3 applied to the DMA
//    GLOBAL SOURCE address and to the fragment READ address (and to the A
//    ds_write address). Involution => logical bytes unchanged.
//  - Raw s_barrier + asm lgkmcnt (never __syncthreads in the loop).
// Stage = A 8 KB + B 8 KB = 16 KB; x3 = 48 KB -> 2 blocks/CU. Grid 512
// (=2/CU, all resident). bid&63 = mt -> A-panel siblings on one XCD.
// ---------------------------------------------------------------------------
__global__ __launch_bounds__(256, 2) void gemm1_kernel(
    const int* __restrict__ X, const char* __restrict__ Btg,
    const int* __restrict__ bsum, const int* __restrict__ H,
    char* __restrict__ A8out) {
  constexpr int K = 3072, KIT = 48;
  __shared__ __align__(16) char smem[49152];
  const int t = threadIdx.x;
  const int bid = blockIdx.x;
  const int mt = bid & 63, nt = bid >> 6;
  const long m0 = (long)mt << 7;
  const int n0 = nt << 7;

  const int lane = t & 63, w = t >> 6;
  const int lc = lane & 31, hg = lane >> 5;
  const int wm = w >> 1, wn = w & 1;

  v16i acc[2][2] = {};

  // ---- A staging (register pack path): thread t -> row t>>1, 32-int half
  const int arow = t >> 1, ahalf = t & 1;
  const int* Xrow = X + (m0 + arow) * (long)K + ahalf * 32;
  const int abase = arow * 64;                       // byte base in A region
  const int asw0 = ((ahalf * 2 + 0) ^ (arow & 3)) * 16;
  const int asw1 = ((ahalf * 2 + 1) ^ (arow & 3)) * 16;

  // ---- B staging (DMA): wave w covers rows w*32 + j*16 + (lane>>2)
  const int brow = w * 32 + (lane >> 2);
  const int bchunk = ((lane & 3) ^ ((lane >> 2) & 3)) * 16;  // src swizzle
  const char* Bsrc = Btg + (long)(n0 + brow) * K + bchunk;   // j=1: +16*K

  // ---- fragment read offsets (row&3 == lc&3 for all frag rows)
  const int fa_row = wm * 64 + lc;
  const int fb_row = wn * 64 + lc;
  const int sel0 = ((0 * 2 + hg) ^ (lc & 3)) * 16;   // ks=0 chunk
  const int sel1 = ((1 * 2 + hg) ^ (lc & 3)) * 16;   // ks=1 chunk

  int4 pX[8], pY[8];                                 // named prefetch sets

  auto A_ISSUE = [&](int4 (&P)[8], int kt) {
    const int* p_ = Xrow + kt * 64;
    #pragma unroll
    for (int i = 0; i < 8; ++i) P[i] = *(const int4*)(p_ + i * 4);
  };
  auto B_ISSUE = [&](int kt, int st) {
    const char* g_ = Bsrc + (long)kt * 64;
    char* l_ = smem + st * 16384 + 8192 + w * 2048;
    async_ld16(g_, l_);
    async_ld16(g_ + 16 * (long)K, l_ + 1024);
  };
  auto A_WRITE = [&](int4 (&P)[8], int st) {
    char* l_ = smem + st * 16384 + abase;
    *(int4*)(l_ + asw0) = make_int4(
        pack4i(P[0].x, P[0].y, P[0].z, P[0].w),
        pack4i(P[1].x, P[1].y, P[1].z, P[1].w),
        pack4i(P[2].x, P[2].y, P[2].z, P[2].w),
        pack4i(P[3].x, P[3].y, P[3].z, P[3].w));
    *(int4*)(l_ + asw1) = make_int4(
        pack4i(P[4].x, P[4].y, P[4].z, P[4].w),
        pack4i(P[5].x, P[5].y, P[5].z, P[5].w),
        pack4i(P[6].x, P[6].y, P[6].z, P[6].w),
        pack4i(P[7].x, P[7].y, P[7].z, P[7].w));
  };
  auto MSTEP = [&](int st) {
    const char* ab = smem + st * 16384;
    const char* bb = ab + 8192;
    __builtin_amdgcn_s_setprio(1);
    {
      v4i a0 = *(const v4i*)(ab + fa_row * 64 + sel0);
      v4i a1 = *(const v4i*)(ab + (fa_row + 32) * 64 + sel0);
      v4i b0 = *(const v4i*)(bb + fb_row * 64 + sel0);
      v4i b1 = *(const v4i*)(bb + (fb_row + 32) * 64 + sel0);
      acc[0][0] = MFMA_I8(a0, b0, acc[0][0]);
      acc[0][1] = MFMA_I8(a0, b1, acc[0][1]);
      acc[1][0] = MFMA_I8(a1, b0, acc[1][0]);
      acc[1][1] = MFMA_I8(a1, b1, acc[1][1]);
    }
    {
      v4i a0 = *(const v4i*)(ab + fa_row * 64 + sel1);
      v4i a1 = *(const v4i*)(ab + (fa_row + 32) * 64 + sel1);
      v4i b0 = *(const v4i*)(bb + fb_row * 64 + sel1);
      v4i b1 = *(const v4i*)(bb + (fb_row + 32) * 64 + sel1);
      acc[0][0] = MFMA_I8(a0, b0, acc[0][0]);
      acc[0][1] = MFMA_I8(a0, b1, acc[0][1]);
      acc[1][0] = MFMA_I8(a1, b0, acc[1][0]);
      acc[1][1] = MFMA_I8(a1, b1, acc[1][1]);
    }
    __builtin_amdgcn_s_setprio(0);
  };

  // Prologue: issue steps 0,1 (10 VMEM ops each); write A(0); sync.
  A_ISSUE(pX, 0); B_ISSUE(0, 0);
  A_ISSUE(pY, 1); B_ISSUE(1, 1);
  WAITV(10);                 // step-0 ops landed (<=10 left = step-1's)
  A_WRITE(pX, 0);
  BARX;

  // Main loop: per half-iter exactly 10 VMEM ops issued; vmcnt(10) => the
  // PREVIOUS half's ops landed while this half's stay in flight.
  for (int kt = 0; kt < KIT - 2; kt += 2) {
    A_ISSUE(pX, kt + 2); B_ISSUE(kt + 2, (kt + 2) % 3);
    MSTEP(kt % 3);
    WAITV(10);
    A_WRITE(pY, (kt + 1) % 3);
    BARX;
    A_ISSUE(pY, kt + 3); B_ISSUE(kt + 3, (kt + 3) % 3);
    MSTEP((kt + 1) % 3);
    WAITV(10);
    A_WRITE(pX, (kt + 2) % 3);
    BARX;
  }
  // Tail: steps KIT-2, KIT-1 (no new issues).
  MSTEP((KIT - 2) % 3);
  WAITV(0);
  A_WRITE(pY, (KIT - 1) % 3);
  BARX;
  MSTEP((KIT - 1) % 3);

  // Epilogue: LDS transpose (stride 136) + SWAR-add trunc8(H int32) -> A8out.
  BARX;
  const int bsv0 = bsum[n0 + wn * 64 + lc];
  const int bsv1 = bsum[n0 + wn * 64 + 32 + lc];
  #pragma unroll
  for (int i = 0; i < 2; ++i) {
    #pragma unroll
    for (int j = 0; j < 2; ++j) {
      const int bv = j ? bsv1 : bsv0;
      const int col = wn * 64 + j * 32 + lc;
      #pragma unroll
      for (int r = 0; r < 16; ++r) {
        const int row = wm * 64 + i * 32 + (hg << 2) + (r & 3) + ((r >> 2) << 3);
        smem[row * 136 + col] = (char)(acc[i][j][r] + bv);
      }
    }
  }
  BARX;
  const char* srcp = smem + (t >> 1) * 136 + (t & 1) * 64;
  const long gco = (m0 + (t >> 1)) * 1024 + n0 + (t & 1) * 64;
  const int* hp = H + gco;
  #pragma unroll
  for (int g = 0; g < 4; ++g) {
    int4 s  = *(const int4*)(srcp + g * 16);
    int4 h0 = *(const int4*)(hp + g * 16);
    int4 h1 = *(const int4*)(hp + g * 16 + 4);
    int4 h2 = *(const int4*)(hp + g * 16 + 8);
    int4 h3 = *(const int4*)(hp + g * 16 + 12);
    s = make_int4(badd4(s.x, pack4i(h0.x, h0.y, h0.z, h0.w)),
                  badd4(s.y, pack4i(h1.x, h1.y, h1.z, h1.w)),
                  badd4(s.z, pack4i(h2.x, h2.y, h2.z, h2.w)),
                  badd4(s.w, pack4i(h3.x, h3.y, h3.z, h3.w)));
    *(int4*)(A8out + gco + g * 16) = s;
  }
}

// ---------------------------------------------------------------------------
// R5 gemm2: same 128x128 3-stage pipeline, both operands int8 via
// global_load_lds (4 DMA ops/step/wave -> vmcnt(4)). K=1024, 16 steps.
// Epilogue: Iout = trunc8(acc+bs) as int32, direct (R4-verified mapping).
// ---------------------------------------------------------------------------
__global__ __launch_bounds__(256, 2) void gemm2_kernel(
    const char* __restrict__ A, const char* __restrict__ Btg,
    const int* __restrict__ bsum, int* __restrict__ Iout) {
  constexpr int K = 1024, KIT = 16;
  __shared__ __align__(16) char smem[49152];
  const int t = threadIdx.x;
  const int bid = blockIdx.x;
  const int mt = bid & 63, nt = bid >> 6;
  const long m0 = (long)mt << 7;
  const int n0 = nt << 7;

  const int lane = t & 63, w = t >> 6;
  const int lc = lane & 31, hg = lane >> 5;
  const int wm = w >> 1, wn = w & 1;

  v16i acc[2][2] = {};

  const int drow = w * 32 + (lane >> 2);             // DMA row (per j: +16)
  const int dchunk = ((lane & 3) ^ ((lane >> 2) & 3)) * 16;
  const char* Asrc = A   + (m0 + drow) * (long)K + dchunk;
  const char* Bsrc = Btg + (long)(n0 + drow) * K + dchunk;

  const int fa_row = wm * 64 + lc;
  const int fb_row = wn * 64 + lc;
  const int sel0 = ((0 * 2 + hg) ^ (lc & 3)) * 16;
  const int sel1 = ((1 * 2 + hg) ^ (lc & 3)) * 16;

  auto ISSUE = [&](int kt, int st) {
    const char* ga = Asrc + (long)kt * 64;
    const char* gb = Bsrc + (long)kt * 64;
    char* la = smem + st * 16384 + w * 2048;
    char* lb = la + 8192;
    async_ld16(ga, la);
    async_ld16(ga + 16 * (long)K, la + 1024);
    async_ld16(gb, lb);
    async_ld16(gb + 16 * (long)K, lb + 1024);
  };
  auto MSTEP = [&](int st) {
    const char* ab = smem + st * 16384;
    const char* bb = ab + 8192;
    __builtin_amdgcn_s_setprio(1);
    {
      v4i a0 = *(const v4i*)(ab + fa_row * 64 + sel0);
      v4i a1 = *(const v4i*)(ab + (fa_row + 32) * 64 + sel0);
      v4i b0 = *(const v4i*)(bb + fb_row * 64 + sel0);
      v4i b1 = *(const v4i*)(bb + (fb_row + 32) * 64 + sel0);
      acc[0][0] = MFMA_I8(a0, b0, acc[0][0]);
      acc[0][1] = MFMA_I8(a0, b1, acc[0][1]);
      acc[1][0] = MFMA_I8(a1, b0, acc[1][0]);
      acc[1][1] = MFMA_I8(a1, b1, acc[1][1]);
    }
    {
      v4i a0 = *(const v4i*)(ab + fa_row * 64 + sel1);
      v4i a1 = *(const v4i*)(ab + (fa_row + 32) * 64 + sel1);
      v4i b0 = *(const v4i*)(bb + fb_row * 64 + sel1);
      v4i b1 = *(const v4i*)(bb + (fb_row + 32) * 64 + sel1);
      acc[0][0] = MFMA_I8(a0, b0, acc[0][0]);
      acc[0][1] = MFMA_I8(a0, b1, acc[0][1]);
      acc[1][0] = MFMA_I8(a1, b0, acc[1][0]);
      acc[1][1] = MFMA_I8(a1, b1, acc[1][1]);
    }
    __builtin_amdgcn_s_setprio(0);
  };

  ISSUE(0, 0);
  ISSUE(1, 1);
  WAITV(4);                  // step-0 DMAs landed
  BARX;
  for (int kt = 0; kt < KIT - 2; ++kt) {
    ISSUE(kt + 2, (kt + 2) % 3);
    MSTEP(kt % 3);
    WAITV(4);                // step kt+1 landed; step kt+2 in flight
    BARX;
  }
  MSTEP((KIT - 2) % 3);
  WAITV(0);
  BARX;
  MSTEP((KIT - 1) % 3);

  // Epilogue: direct int32 stores (mapping verified R4).
  const int bsj0 = bsum[n0 + wn * 64 + lc];
  const int bsj1 = bsum[n0 + wn * 64 + 32 + lc];
  #pragma unroll
  for (int i = 0; i < 2; ++i) {
    #pragma unroll
    for (int j = 0; j < 2; ++j) {
      const int bv = j ? bsj1 : bsj0;
      const int col = n0 + wn * 64 + j * 32 + lc;
      #pragma unroll
      for (int r = 0; r < 16; ++r) {
        const long row = m0 + wm * 64 + i * 32 + (hg << 2) + (r & 3) + ((r >> 2) << 3);
        Iout[row * 1024 + col] = (int)(signed char)(acc[i][j][r] + bv);
      }
    }
  }
}

// ---------------------------------------------------------------------------
// Layer 3: 16x128 tile, 512 blocks (2/CU), mfma_i32_16x16x64_i8, 2-stage.
// A = h2 int32 from d_out, packed to int8 in staging. (Verified R7/R8.)
// ---------------------------------------------------------------------------
__global__ __launch_bounds__(256, 2) void gemm3_kernel(
    const int* __restrict__ h2, const char* __restrict__ Btg,
    const int* __restrict__ bsum, int* __restrict__ Iout) {
  // stage: As 16x80 (1280) + Bs 128x80 (10240) = 11520; x2 = 23040
  __shared__ __align__(16) char smem[23040];
  const int t = threadIdx.x;
  const int m0 = blockIdx.x << 4;
  const int lane = t & 63, w = t >> 6;
  const int l16 = lane & 15, q = lane >> 4;
  v4i acc0 = {}, acc1 = {};

  const int am = t >> 4, ah = t & 15;      // 16 rows x 16 thr x 4 ints
  const int* Arow = h2 + (long)(m0 + am) * 1024 + ah * 4;
  const int aoff = am * 80 + ah * 4;
  const int bm = t >> 1, bh = t & 1;       // 128 rows x 2 thr x 32 B
  const char* Brow = Btg + (long)bm * 1024 + bh * 32;
  const int boff = bm * 80 + bh * 32;

  const int abo  = l16 * 80 + q * 16;
  const int bbo0 = (w * 32 + l16) * 80 + q * 16;
  const int bbo1 = (w * 32 + 16 + l16) * 80 + q * 16;

  int4 ar, br0, br1;
  auto LOAD = [&](int kt) {
    const int kb = kt << 6;
    ar  = *(const int4*)(Arow + kb);
    br0 = *(const int4*)(Brow + kb);
    br1 = *(const int4*)(Brow + kb + 16);
  };
  auto STORE = [&](int stage) {
    char* base = smem + stage * 11520;
    *(int*)(base + aoff) = pack4i(ar.x, ar.y, ar.z, ar.w);
    *(int4*)(base + 1280 + boff)      = br0;
    *(int4*)(base + 1280 + boff + 16) = br1;
  };
  auto MFMA = [&](int stage) {
    const char* base = smem + stage * 11520;
    v4i a  = *(const v4i*)(base + abo);
    v4i b0 = *(const v4i*)(base + 1280 + bbo0);
    v4i b1 = *(const v4i*)(base + 1280 + bbo1);
    acc0 = __builtin_amdgcn_mfma_i32_16x16x64_i8(a, b0, acc0, 0, 0, 0);
    acc1 = __builtin_amdgcn_mfma_i32_16x16x64_i8(a, b1, acc1, 0, 0, 0);
  };

  LOAD(0); STORE(0); __syncthreads();
  for (int kt = 0; kt < 16; ++kt) {
    if (kt + 1 < 16) LOAD(kt + 1);
    MFMA(kt & 1);
    if (kt + 1 < 16) { STORE((kt + 1) & 1); __syncthreads(); }
  }

  const int c0 = w * 32 + l16;       // cols {0-15,32-47,64-79,96-111}
  const int c1 = c0 + 16;            // cols {16-31,48-63,80-95,112-127}
  if (c0 < 100) {
    const int b = bsum[c0];
    #pragma unroll
    for (int r = 0; r < 4; ++r)
      Iout[(long)(m0 + q * 4 + r) * 100 + c0] = (int)(signed char)(acc0[r] + b);
  }
  if (c1 < 100) {
    const int b = bsum[c1];
    #pragma unroll
    for (int r = 0; r < 4; ++r)
      Iout[(long)(m0 + q * 4 + r) * 100 + c1] = (int)(signed char)(acc1[r] + b);
  }
}

// ---------------------------------------------------------------------------
// ws (12.7 MB): Bt1 | Bt2 | Bt3 | bs1 | bs2 | bs3 | A2
// ---------------------------------------------------------------------------
extern "C" void kernel_launch(void* const* d_in, const int* in_sizes, int n_in,
                              void* d_out, int out_size, void* d_ws, size_t ws_size,
                              hipStream_t stream) {
  (void)in_sizes; (void)n_in; (void)out_size; (void)ws_size;
  const int* W1  = (const int*)d_in[0];
  const int* b1  = (const int*)d_in[1];
  const int* W2  = (const int*)d_in[2];
  const int* b2  = (const int*)d_in[3];
  const int* W3  = (const int*)d_in[4];
  const int* b3  = (const int*)d_in[5];
  const int* E1  = (const int*)d_in[6];
  const int* eb1 = (const int*)d_in[7];
  const int* E2  = (const int*)d_in[8];
  const int* eb2 = (const int*)d_in[9];
  const int* E3  = (const int*)d_in[10];
  const int* eb3 = (const int*)d_in[11];
  const int* X   = (const int*)d_in[12];   // [8192][3072] int32
  const int* H   = (const int*)d_in[13];   // [8192][1024] int32
  int* out = (int*)d_out;                  // h2 [8192*1024] then out [8192*100]

  char* ws  = (char*)d_ws;
  char* Bt1 = ws;                          // 3,145,728
  char* Bt2 = Bt1 + 3145728;               // 1,048,576
  char* Bt3 = Bt2 + 1048576;               //   131,072 (rows 100..127 zeroed)
  int*  bs1 = (int*)(Bt3 + 131072);        // 1024 ints
  int*  bs2 = bs1 + 1024;                  // 1024 ints
  int*  bs3 = bs2 + 1024;                  //  128 ints
  char* A2  = (char*)(bs3 + 128);          // 8,388,608 int8

  pack_weights_kernel<<<dim3(265), dim3(256), 0, stream>>>(
      W1, E1, Bt1, W2, E2, Bt2, W3, E3, Bt3,
      b1, eb1, bs1, b2, eb2, bs2, b3, eb3, bs3);

  // Layer 1: X (int32, fused pack) -> i2c ; epilogue adds trunc8(H) -> A2
  gemm1_kernel<<<dim3(512), dim3(256), 0, stream>>>(X, Bt1, bs1, H, A2);

  // Layer 2: h2 -> d_out (int32)
  gemm2_kernel<<<dim3(512), dim3(256), 0, stream>>>(A2, Bt2, bs2, out);

  // Layer 3: reads h2 from d_out (int32), writes out region (int32)
  gemm3_kernel<<<dim3(512), dim3(256), 0, stream>>>(
      out, Bt3, bs3, out + 8388608);
}

// Round 6
// 319.321 us; speedup vs baseline: 1.1122x; 1.1122x over previous
//
#include <hip/hip_runtime.h>

typedef int v4i  __attribute__((ext_vector_type(4)));
typedef int v16i __attribute__((ext_vector_type(16)));

__device__ __forceinline__ int pack4i(int a, int b, int c, int d) {
  return (a & 255) | ((b & 255) << 8) | ((c & 255) << 16) | ((d & 255) << 24);
}
// SWAR per-byte add (mod-256 per lane-byte)
__device__ __forceinline__ int badd4(int a, int b) {
  return ((a & 0x7f7f7f7f) + (b & 0x7f7f7f7f)) ^ ((a ^ b) & 0x80808080);
}

#define MFMA_I8(a, b, c) __builtin_amdgcn_mfma_i32_32x32x32_i8(a, b, c, 0, 0, 0)
// Counted waits + raw barrier (R5-verified correct): __syncthreads would
// drain vmcnt to 0 and kill the pipeline. BARX orders ds ops then syncs.
#define WAITV(N) asm volatile("s_waitcnt vmcnt(" #N ")" ::: "memory")
#define BARX do { asm volatile("s_waitcnt lgkmcnt(0)" ::: "memory"); \
                  __builtin_amdgcn_s_barrier(); } while (0)

// ---------------------------------------------------------------------------
// Pack (W + E) -> int8, transposed Bt[n][k] (row stride K bytes).
// Tile: 64 n x 256 k per block, 256 threads. Zero-pads n >= N rows.
// ---------------------------------------------------------------------------
__device__ void pack_tile(const int* __restrict__ W, const int* __restrict__ E,
                          char* __restrict__ Bt, int K, int N,
                          int nx, int ky, char* lin) {
  const int t = threadIdx.x;
  const int n0 = nx * 64, k0 = ky * 256;
  {
    const int c  = t & 15;          // column group: 4 ints = 16 B
    const int kq = t >> 4;          // 0..15
    const int ng = n0 + c * 4;
    #pragma unroll 4
    for (int s = 0; s < 16; ++s) {
      const int k = s * 16 + kq;
      const long grow = (long)(k0 + k) * N;
      int a0, a1, a2, a3;
      if (ng + 3 < N) {
        int4 wv = *(const int4*)(W + grow + ng);
        int4 ev = *(const int4*)(E + grow + ng);
        a0 = wv.x + ev.x; a1 = wv.y + ev.y; a2 = wv.z + ev.z; a3 = wv.w + ev.w;
      } else {
        a0 = (ng + 0 < N) ? W[grow + ng + 0] + E[grow + ng + 0] : 0;
        a1 = (ng + 1 < N) ? W[grow + ng + 1] + E[grow + ng + 1] : 0;
        a2 = (ng + 2 < N) ? W[grow + ng + 2] + E[grow + ng + 2] : 0;
        a3 = (ng + 3 < N) ? W[grow + ng + 3] + E[grow + ng + 3] : 0;
      }
      *(int*)(lin + k * 68 + c * 4) = pack4i(a0, a1, a2, a3);
    }
  }
  __syncthreads();
  {
    const int n = t & 63, kq = t >> 6;
    char* dst = Bt + (long)(n0 + n) * K + k0 + (kq << 6);
    int outv[16];
    #pragma unroll
    for (int g = 0; g < 16; ++g) {
      const int k = (kq << 6) + (g << 2);
      outv[g] = pack4i(lin[(k + 0) * 68 + n], lin[(k + 1) * 68 + n],
                       lin[(k + 2) * 68 + n], lin[(k + 3) * 68 + n]);
    }
    #pragma unroll
    for (int g = 0; g < 4; ++g)
      *(int4*)(dst + (g << 4)) =
          make_int4(outv[g * 4], outv[g * 4 + 1], outv[g * 4 + 2], outv[g * 4 + 3]);
  }
}

__global__ __launch_bounds__(256) void pack_weights_kernel(
    const int* W1, const int* E1, char* Bt1,
    const int* W2, const int* E2, char* Bt2,
    const int* W3, const int* E3, char* Bt3,
    const int* b1, const int* eb1, int* bs1,
    const int* b2, const int* eb2, int* bs2,
    const int* b3, const int* eb3, int* bs3) {
  __shared__ __align__(16) char smem[17408];
  const int bid = blockIdx.x;
  if (bid < 192) {
    pack_tile(W1, E1, Bt1, 3072, 1024, bid % 16, bid / 16, smem);
  } else if (bid < 256) {
    const int l = bid - 192;
    pack_tile(W2, E2, Bt2, 1024, 1024, l % 16, l / 16, smem);
  } else if (bid < 264) {
    const int l = bid - 256;
    pack_tile(W3, E3, Bt3, 1024, 100, l & 1, l >> 1, smem);
  } else {
    const int t = threadIdx.x;
    for (int i = t; i < 1024; i += 256) {
      bs1[i] = b1[i] + eb1[i];
      bs2[i] = b2[i] + eb2[i];
    }
    for (int i = t; i < 128; i += 256)
      bs3[i] = (i < 100) ? (b3[i] + eb3[i]) : 0;
  }
}

// ---------------------------------------------------------------------------
// R6 gemm1: 128x128 tile, BK=64, 256 thr (4 waves 2x2), grid 512 (2 blk/CU),
// 3-stage LDS + depth-2 named-register prefetch + counted vmcnt.
//   R4 lesson: 80 B LDS row stride = ~2-way conflicts (free); keep it.
//   R5 lesson: 64 B rows + XOR swizzle = 4-way conflicts (11M); dropped.
//   R4 lesson: grid 256 = 1 blk/CU -> barrier drain stalls whole CU; now 2.
// Per thread per K-step: exactly 10 global loads (8 A-int4 + 2 B-int4), so
// WAITV(10) after issuing step t+2 drains step t+1's set while t+2's ten
// stay in flight. Global mapping: 4 thr/row x 16 B -> each load instruction
// touches 16 fully-used 64 B lines. bid&63 = mt -> A-panel siblings on one
// XCD L2. Stage = A[128][80] + B[128][80] = 20480 B; x3 = 61440.
// ---------------------------------------------------------------------------
__global__ __launch_bounds__(256, 2) void gemm1_kernel(
    const int* __restrict__ X, const char* __restrict__ Btg,
    const int* __restrict__ bsum, const int* __restrict__ H,
    char* __restrict__ A8out) {
  constexpr int K = 3072, KIT = 48;
  __shared__ __align__(16) char smem[61440];
  const int t = threadIdx.x;
  const int bid = blockIdx.x;
  const int mt = bid & 63, nt = bid >> 6;
  const long m0 = (long)mt << 7;
  const int n0 = nt << 7;

  const int lane = t & 63, w = t >> 6;
  const int lc = lane & 31, hg = lane >> 5;
  const int wm = w >> 1, wn = w & 1;

  v16i acc[2][2] = {};

  // staging mapping: row r = t>>2 (and r+64), quarter q = t&3 (16 B each)
  const int r = t >> 2, q = t & 3;
  const int* Xr0 = X + (m0 + r) * (long)K + q * 16;
  const int* Xr1 = Xr0 + (long)64 * K;
  const char* Br0 = Btg + (long)(n0 + r) * K + q * 16;
  const char* Br1 = Br0 + (long)64 * K;
  const int awo = r * 80 + q * 16;
  const int bwo = 10240 + r * 80 + q * 16;

  // fragment read bases (80 B stride, chunk = ks*32 + hg*16)
  const int fa = (wm * 64 + lc) * 80;
  const int fb = 10240 + (wn * 64 + lc) * 80;

  int4 xA[8], yA[8], xB0, xB1, yB0, yB1;   // named depth-2 prefetch sets

  auto ISSUEX = [&](int kt) {
    const int ko = kt * 64;
    #pragma unroll
    for (int i = 0; i < 4; ++i) xA[i]     = *(const int4*)(Xr0 + ko + i * 4);
    #pragma unroll
    for (int i = 0; i < 4; ++i) xA[4 + i] = *(const int4*)(Xr1 + ko + i * 4);
    xB0 = *(const int4*)(Br0 + ko);
    xB1 = *(const int4*)(Br1 + ko);
  };
  auto ISSUEY = [&](int kt) {
    const int ko = kt * 64;
    #pragma unroll
    for (int i = 0; i < 4; ++i) yA[i]     = *(const int4*)(Xr0 + ko + i * 4);
    #pragma unroll
    for (int i = 0; i < 4; ++i) yA[4 + i] = *(const int4*)(Xr1 + ko + i * 4);
    yB0 = *(const int4*)(Br0 + ko);
    yB1 = *(const int4*)(Br1 + ko);
  };
  auto WRITEX = [&](int st) {
    char* base = smem + st * 20480;
    *(int4*)(base + awo) = make_int4(
        pack4i(xA[0].x, xA[0].y, xA[0].z, xA[0].w),
        pack4i(xA[1].x, xA[1].y, xA[1].z, xA[1].w),
        pack4i(xA[2].x, xA[2].y, xA[2].z, xA[2].w),
        pack4i(xA[3].x, xA[3].y, xA[3].z, xA[3].w));
    *(int4*)(base + awo + 64 * 80) = make_int4(
        pack4i(xA[4].x, xA[4].y, xA[4].z, xA[4].w),
        pack4i(xA[5].x, xA[5].y, xA[5].z, xA[5].w),
        pack4i(xA[6].x, xA[6].y, xA[6].z, xA[6].w),
        pack4i(xA[7].x, xA[7].y, xA[7].z, xA[7].w));
    *(int4*)(base + bwo)           = xB0;
    *(int4*)(base + bwo + 64 * 80) = xB1;
  };
  auto WRITEY = [&](int st) {
    char* base = smem + st * 20480;
    *(int4*)(base + awo) = make_int4(
        pack4i(yA[0].x, yA[0].y, yA[0].z, yA[0].w),
        pack4i(yA[1].x, yA[1].y, yA[1].z, yA[1].w),
        pack4i(yA[2].x, yA[2].y, yA[2].z, yA[2].w),
        pack4i(yA[3].x, yA[3].y, yA[3].z, yA[3].w));
    *(int4*)(base + awo + 64 * 80) = make_int4(
        pack4i(yA[4].x, yA[4].y, yA[4].z, yA[4].w),
        pack4i(yA[5].x, yA[5].y, yA[5].z, yA[5].w),
        pack4i(yA[6].x, yA[6].y, yA[6].z, yA[6].w),
        pack4i(yA[7].x, yA[7].y, yA[7].z, yA[7].w));
    *(int4*)(base + bwo)           = yB0;
    *(int4*)(base + bwo + 64 * 80) = yB1;
  };
  auto MSTEP = [&](int st) {
    const char* base = smem + st * 20480;
    __builtin_amdgcn_s_setprio(1);
    #pragma unroll
    for (int ks = 0; ks < 2; ++ks) {
      const int sel = ks * 32 + hg * 16;
      v4i a0 = *(const v4i*)(base + fa + sel);
      v4i a1 = *(const v4i*)(base + fa + 32 * 80 + sel);
      v4i b0 = *(const v4i*)(base + fb + sel);
      v4i b1 = *(const v4i*)(base + fb + 32 * 80 + sel);
      acc[0][0] = MFMA_I8(a0, b0, acc[0][0]);
      acc[0][1] = MFMA_I8(a0, b1, acc[0][1]);
      acc[1][0] = MFMA_I8(a1, b0, acc[1][0]);
      acc[1][1] = MFMA_I8(a1, b1, acc[1][1]);
    }
    __builtin_amdgcn_s_setprio(0);
  };

  ISSUEX(0);
  ISSUEY(1);
  WAITV(10);            // X-set landed (Y's 10 outstanding)
  WRITEX(0);
  BARX;
  for (int kt = 0; kt < KIT - 2; kt += 2) {
    ISSUEX(kt + 2);     // outstanding: Y(kt+1) 10 + X(kt+2) 10
    MSTEP(kt % 3);
    WAITV(10);          // Y(kt+1) landed; X stays in flight
    WRITEY((kt + 1) % 3);
    BARX;
    ISSUEY(kt + 3);
    MSTEP((kt + 1) % 3);
    WAITV(10);
    WRITEX((kt + 2) % 3);
    BARX;
  }
  MSTEP((KIT - 2) % 3);
  WAITV(0);
  WRITEY((KIT - 1) % 3);
  BARX;
  MSTEP((KIT - 1) % 3);

  // Epilogue (R5-verified): LDS transpose stride 136 + SWAR-add trunc8(H).
  BARX;
  const int bsv0 = bsum[n0 + wn * 64 + lc];
  const int bsv1 = bsum[n0 + wn * 64 + 32 + lc];
  #pragma unroll
  for (int i = 0; i < 2; ++i) {
    #pragma unroll
    for (int j = 0; j < 2; ++j) {
      const int bv = j ? bsv1 : bsv0;
      const int col = wn * 64 + j * 32 + lc;
      #pragma unroll
      for (int rr = 0; rr < 16; ++rr) {
        const int row = wm * 64 + i * 32 + (hg << 2) + (rr & 3) + ((rr >> 2) << 3);
        smem[row * 136 + col] = (char)(acc[i][j][rr] + bv);
      }
    }
  }
  BARX;
  const char* srcp = smem + (t >> 1) * 136 + (t & 1) * 64;
  const long gco = (m0 + (t >> 1)) * 1024 + n0 + (t & 1) * 64;
  const int* hp = H + gco;
  #pragma unroll
  for (int g = 0; g < 4; ++g) {
    int4 s  = *(const int4*)(srcp + g * 16);
    int4 h0 = *(const int4*)(hp + g * 16);
    int4 h1 = *(const int4*)(hp + g * 16 + 4);
    int4 h2 = *(const int4*)(hp + g * 16 + 8);
    int4 h3 = *(const int4*)(hp + g * 16 + 12);
    s = make_int4(badd4(s.x, pack4i(h0.x, h0.y, h0.z, h0.w)),
                  badd4(s.y, pack4i(h1.x, h1.y, h1.z, h1.w)),
                  badd4(s.z, pack4i(h2.x, h2.y, h2.z, h2.w)),
                  badd4(s.w, pack4i(h3.x, h3.y, h3.z, h3.w)));
    *(int4*)(A8out + gco + g * 16) = s;
  }
}

// ---------------------------------------------------------------------------
// R6 gemm2: same template, A already int8 (4 loads/thread/step -> WAITV(4)).
// K=1024, 16 steps. Epilogue: direct int32 stores (R4/R5-verified mapping).
// ---------------------------------------------------------------------------
__global__ __launch_bounds__(256, 2) void gemm2_kernel(
    const char* __restrict__ A, const char* __restrict__ Btg,
    const int* __restrict__ bsum, int* __restrict__ Iout) {
  constexpr int K = 1024, KIT = 16;
  __shared__ __align__(16) char smem[61440];
  const int t = threadIdx.x;
  const int bid = blockIdx.x;
  const int mt = bid & 63, nt = bid >> 6;
  const long m0 = (long)mt << 7;
  const int n0 = nt << 7;

  const int lane = t & 63, w = t >> 6;
  const int lc = lane & 31, hg = lane >> 5;
  const int wm = w >> 1, wn = w & 1;

  v16i acc[2][2] = {};

  const int r = t >> 2, q = t & 3;
  const char* Ar0 = A + (m0 + r) * (long)K + q * 16;
  const char* Ar1 = Ar0 + (long)64 * K;
  const char* Br0 = Btg + (long)(n0 + r) * K + q * 16;
  const char* Br1 = Br0 + (long)64 * K;
  const int awo = r * 80 + q * 16;
  const int bwo = 10240 + r * 80 + q * 16;

  const int fa = (wm * 64 + lc) * 80;
  const int fb = 10240 + (wn * 64 + lc) * 80;

  int4 xA0, xA1, xB0, xB1, yA0, yA1, yB0, yB1;

  auto ISSUEX = [&](int kt) {
    const int ko = kt * 64;
    xA0 = *(const int4*)(Ar0 + ko);
    xA1 = *(const int4*)(Ar1 + ko);
    xB0 = *(const int4*)(Br0 + ko);
    xB1 = *(const int4*)(Br1 + ko);
  };
  auto ISSUEY = [&](int kt) {
    const int ko = kt * 64;
    yA0 = *(const int4*)(Ar0 + ko);
    yA1 = *(const int4*)(Ar1 + ko);
    yB0 = *(const int4*)(Br0 + ko);
    yB1 = *(const int4*)(Br1 + ko);
  };
  auto WRITEX = [&](int st) {
    char* base = smem + st * 20480;
    *(int4*)(base + awo)           = xA0;
    *(int4*)(base + awo + 64 * 80) = xA1;
    *(int4*)(base + bwo)           = xB0;
    *(int4*)(base + bwo + 64 * 80) = xB1;
  };
  auto WRITEY = [&](int st) {
    char* base = smem + st * 20480;
    *(int4*)(base + awo)           = yA0;
    *(int4*)(base + awo + 64 * 80) = yA1;
    *(int4*)(base + bwo)           = yB0;
    *(int4*)(base + bwo + 64 * 80) = yB1;
  };
  auto MSTEP = [&](int st) {
    const char* base = smem + st * 20480;
    __builtin_amdgcn_s_setprio(1);
    #pragma unroll
    for (int ks = 0; ks < 2; ++ks) {
      const int sel = ks * 32 + hg * 16;
      v4i a0 = *(const v4i*)(base + fa + sel);
      v4i a1 = *(const v4i*)(base + fa + 32 * 80 + sel);
      v4i b0 = *(const v4i*)(base + fb + sel);
      v4i b1 = *(const v4i*)(base + fb + 32 * 80 + sel);
      acc[0][0] = MFMA_I8(a0, b0, acc[0][0]);
      acc[0][1] = MFMA_I8(a0, b1, acc[0][1]);
      acc[1][0] = MFMA_I8(a1, b0, acc[1][0]);
      acc[1][1] = MFMA_I8(a1, b1, acc[1][1]);
    }
    __builtin_amdgcn_s_setprio(0);
  };

  ISSUEX(0);
  ISSUEY(1);
  WAITV(4);
  WRITEX(0);
  BARX;
  for (int kt = 0; kt < KIT - 2; kt += 2) {
    ISSUEX(kt + 2);
    MSTEP(kt % 3);
    WAITV(4);
    WRITEY((kt + 1) % 3);
    BARX;
    ISSUEY(kt + 3);
    MSTEP((kt + 1) % 3);
    WAITV(4);
    WRITEX((kt + 2) % 3);
    BARX;
  }
  MSTEP((KIT - 2) % 3);
  WAITV(0);
  WRITEY((KIT - 1) % 3);
  BARX;
  MSTEP((KIT - 1) % 3);

  const int bsj0 = bsum[n0 + wn * 64 + lc];
  const int bsj1 = bsum[n0 + wn * 64 + 32 + lc];
  #pragma unroll
  for (int i = 0; i < 2; ++i) {
    #pragma unroll
    for (int j = 0; j < 2; ++j) {
      const int bv = j ? bsj1 : bsj0;
      const int col = n0 + wn * 64 + j * 32 + lc;
      #pragma unroll
      for (int rr = 0; rr < 16; ++rr) {
        const long row = m0 + wm * 64 + i * 32 + (hg << 2) + (rr & 3) + ((rr >> 2) << 3);
        Iout[row * 1024 + col] = (int)(signed char)(acc[i][j][rr] + bv);
      }
    }
  }
}

// ---------------------------------------------------------------------------
// Layer 3: 16x128 tile, 512 blocks (2/CU), mfma_i32_16x16x64_i8, 2-stage.
// A = h2 int32 from d_out, packed to int8 in staging. (Long-verified.)
// ---------------------------------------------------------------------------
__global__ __launch_bounds__(256, 2) void gemm3_kernel(
    const int* __restrict__ h2, const char* __restrict__ Btg,
    const int* __restrict__ bsum, int* __restrict__ Iout) {
  // stage: As 16x80 (1280) + Bs 128x80 (10240) = 11520; x2 = 23040
  __shared__ __align__(16) char smem[23040];
  const int t = threadIdx.x;
  const int m0 = blockIdx.x << 4;
  const int lane = t & 63, w = t >> 6;
  const int l16 = lane & 15, q = lane >> 4;
  v4i acc0 = {}, acc1 = {};

  const int am = t >> 4, ah = t & 15;      // 16 rows x 16 thr x 4 ints
  const int* Arow = h2 + (long)(m0 + am) * 1024 + ah * 4;
  const int aoff = am * 80 + ah * 4;
  const int bm = t >> 1, bh = t & 1;       // 128 rows x 2 thr x 32 B
  const char* Brow = Btg + (long)bm * 1024 + bh * 32;
  const int boff = bm * 80 + bh * 32;

  const int abo  = l16 * 80 + q * 16;
  const int bbo0 = (w * 32 + l16) * 80 + q * 16;
  const int bbo1 = (w * 32 + 16 + l16) * 80 + q * 16;

  int4 ar, br0, br1;
  auto LOAD = [&](int kt) {
    const int kb = kt << 6;
    ar  = *(const int4*)(Arow + kb);
    br0 = *(const int4*)(Brow + kb);
    br1 = *(const int4*)(Brow + kb + 16);
  };
  auto STORE = [&](int stage) {
    char* base = smem + stage * 11520;
    *(int*)(base + aoff) = pack4i(ar.x, ar.y, ar.z, ar.w);
    *(int4*)(base + 1280 + boff)      = br0;
    *(int4*)(base + 1280 + boff + 16) = br1;
  };
  auto MFMA = [&](int stage) {
    const char* base = smem + stage * 11520;
    v4i a  = *(const v4i*)(base + abo);
    v4i b0 = *(const v4i*)(base + 1280 + bbo0);
    v4i b1 = *(const v4i*)(base + 1280 + bbo1);
    acc0 = __builtin_amdgcn_mfma_i32_16x16x64_i8(a, b0, acc0, 0, 0, 0);
    acc1 = __builtin_amdgcn_mfma_i32_16x16x64_i8(a, b1, acc1, 0, 0, 0);
  };

  LOAD(0); STORE(0); __syncthreads();
  for (int kt = 0; kt < 16; ++kt) {
    if (kt + 1 < 16) LOAD(kt + 1);
    MFMA(kt & 1);
    if (kt + 1 < 16) { STORE((kt + 1) & 1); __syncthreads(); }
  }

  const int c0 = w * 32 + l16;       // cols {0-15,32-47,64-79,96-111}
  const int c1 = c0 + 16;            // cols {16-31,48-63,80-95,112-127}
  if (c0 < 100) {
    const int b = bsum[c0];
    #pragma unroll
    for (int rr = 0; rr < 4; ++rr)
      Iout[(long)(m0 + q * 4 + rr) * 100 + c0] = (int)(signed char)(acc0[rr] + b);
  }
  if (c1 < 100) {
    const int b = bsum[c1];
    #pragma unroll
    for (int rr = 0; rr < 4; ++rr)
      Iout[(long)(m0 + q * 4 + rr) * 100 + c1] = (int)(signed char)(acc1[rr] + b);
  }
}

// ---------------------------------------------------------------------------
// ws (12.7 MB): Bt1 | Bt2 | Bt3 | bs1 | bs2 | bs3 | A2
// ---------------------------------------------------------------------------
extern "C" void kernel_launch(void* const* d_in, const int* in_sizes, int n_in,
                              void* d_out, int out_size, void* d_ws, size_t ws_size,
                              hipStream_t stream) {
  (void)in_sizes; (void)n_in; (void)out_size; (void)ws_size;
  const int* W1  = (const int*)d_in[0];
  const int* b1  = (const int*)d_in[1];
  const int* W2  = (const int*)d_in[2];
  const int* b2  = (const int*)d_in[3];
  const int* W3  = (const int*)d_in[4];
  const int* b3  = (const int*)d_in[5];
  const int* E1  = (const int*)d_in[6];
  const int* eb1 = (const int*)d_in[7];
  const int* E2  = (const int*)d_in[8];
  const int* eb2 = (const int*)d_in[9];
  const int* E3  = (const int*)d_in[10];
  const int* eb3 = (const int*)d_in[11];
  const int* X   = (const int*)d_in[12];   // [8192][3072] int32
  const int* H   = (const int*)d_in[13];   // [8192][1024] int32
  int* out = (int*)d_out;                  // h2 [8192*1024] then out [8192*100]

  char* ws  = (char*)d_ws;
  char* Bt1 = ws;                          // 3,145,728
  char* Bt2 = Bt1 + 3145728;               // 1,048,576
  char* Bt3 = Bt2 + 1048576;               //   131,072 (rows 100..127 zeroed)
  int*  bs1 = (int*)(Bt3 + 131072);        // 1024 ints
  int*  bs2 = bs1 + 1024;                  // 1024 ints
  int*  bs3 = bs2 + 1024;                  //  128 ints
  char* A2  = (char*)(bs3 + 128);          // 8,388,608 int8

  pack_weights_kernel<<<dim3(265), dim3(256), 0, stream>>>(
      W1, E1, Bt1, W2, E2, Bt2, W3, E3, Bt3,
      b1, eb1, bs1, b2, eb2, bs2, b3, eb3, bs3);

  // Layer 1: X (int32, fused pack) -> i2c ; epilogue adds trunc8(H) -> A2
  gemm1_kernel<<<dim3(512), dim3(256), 0, stream>>>(X, Bt1, bs1, H, A2);

  // Layer 2: h2 -> d_out (int32)
  gemm2_kernel<<<dim3(512), dim3(256), 0, stream>>>(A2, Bt2, bs2, out);

  // Layer 3: reads h2 from d_out (int32), writes out region (int32)
  gemm3_kernel<<<dim3(512), dim3(256), 0, stream>>>(
      out, Bt3, bs3, out + 8388608);
}

// Round 7
// 295.851 us; speedup vs baseline: 1.2004x; 1.0793x over previous
//
#include <hip/hip_runtime.h>

typedef int v4i  __attribute__((ext_vector_type(4)));
typedef int v16i __attribute__((ext_vector_type(16)));

__device__ __forceinline__ int pack4i(int a, int b, int c, int d) {
  return (a & 255) | ((b & 255) << 8) | ((c & 255) << 16) | ((d & 255) << 24);
}
// SWAR per-byte add (mod-256 per lane-byte)
__device__ __forceinline__ int badd4(int a, int b) {
  return ((a & 0x7f7f7f7f) + (b & 0x7f7f7f7f)) ^ ((a ^ b) & 0x80808080);
}

#define MFMA_I8(a, b, c) __builtin_amdgcn_mfma_i32_32x32x32_i8(a, b, c, 0, 0, 0)
// Counted waits + raw barrier (R5/R6-verified correct): __syncthreads would
// drain vmcnt to 0 and kill the pipeline. BARX orders ds ops then syncs.
#define WAITV(N) asm volatile("s_waitcnt vmcnt(" #N ")" ::: "memory")
#define BARX do { asm volatile("s_waitcnt lgkmcnt(0)" ::: "memory"); \
                  __builtin_amdgcn_s_barrier(); } while (0)

// ---------------------------------------------------------------------------
// Pack (W + E) -> int8, transposed Bt[n][k] (row stride K bytes).
// Tile: 64 n x 256 k per block, 256 threads. Zero-pads n >= N rows.
// ---------------------------------------------------------------------------
__device__ void pack_tile(const int* __restrict__ W, const int* __restrict__ E,
                          char* __restrict__ Bt, int K, int N,
                          int nx, int ky, char* lin) {
  const int t = threadIdx.x;
  const int n0 = nx * 64, k0 = ky * 256;
  {
    const int c  = t & 15;          // column group: 4 ints = 16 B
    const int kq = t >> 4;          // 0..15
    const int ng = n0 + c * 4;
    #pragma unroll 4
    for (int s = 0; s < 16; ++s) {
      const int k = s * 16 + kq;
      const long grow = (long)(k0 + k) * N;
      int a0, a1, a2, a3;
      if (ng + 3 < N) {
        int4 wv = *(const int4*)(W + grow + ng);
        int4 ev = *(const int4*)(E + grow + ng);
        a0 = wv.x + ev.x; a1 = wv.y + ev.y; a2 = wv.z + ev.z; a3 = wv.w + ev.w;
      } else {
        a0 = (ng + 0 < N) ? W[grow + ng + 0] + E[grow + ng + 0] : 0;
        a1 = (ng + 1 < N) ? W[grow + ng + 1] + E[grow + ng + 1] : 0;
        a2 = (ng + 2 < N) ? W[grow + ng + 2] + E[grow + ng + 2] : 0;
        a3 = (ng + 3 < N) ? W[grow + ng + 3] + E[grow + ng + 3] : 0;
      }
      *(int*)(lin + k * 68 + c * 4) = pack4i(a0, a1, a2, a3);
    }
  }
  __syncthreads();
  {
    const int n = t & 63, kq = t >> 6;
    char* dst = Bt + (long)(n0 + n) * K + k0 + (kq << 6);
    int outv[16];
    #pragma unroll
    for (int g = 0; g < 16; ++g) {
      const int k = (kq << 6) + (g << 2);
      outv[g] = pack4i(lin[(k + 0) * 68 + n], lin[(k + 1) * 68 + n],
                       lin[(k + 2) * 68 + n], lin[(k + 3) * 68 + n]);
    }
    #pragma unroll
    for (int g = 0; g < 4; ++g)
      *(int4*)(dst + (g << 4)) =
          make_int4(outv[g * 4], outv[g * 4 + 1], outv[g * 4 + 2], outv[g * 4 + 3]);
  }
}

__global__ __launch_bounds__(256) void pack_weights_kernel(
    const int* W1, const int* E1, char* Bt1,
    const int* W2, const int* E2, char* Bt2,
    const int* W3, const int* E3, char* Bt3,
    const int* b1, const int* eb1, int* bs1,
    const int* b2, const int* eb2, int* bs2,
    const int* b3, const int* eb3, int* bs3) {
  __shared__ __align__(16) char smem[17408];
  const int bid = blockIdx.x;
  if (bid < 192) {
    pack_tile(W1, E1, Bt1, 3072, 1024, bid % 16, bid / 16, smem);
  } else if (bid < 256) {
    const int l = bid - 192;
    pack_tile(W2, E2, Bt2, 1024, 1024, l % 16, l / 16, smem);
  } else if (bid < 264) {
    const int l = bid - 256;
    pack_tile(W3, E3, Bt3, 1024, 100, l & 1, l >> 1, smem);
  } else {
    const int t = threadIdx.x;
    for (int i = t; i < 1024; i += 256) {
      bs1[i] = b1[i] + eb1[i];
      bs2[i] = b2[i] + eb2[i];
    }
    for (int i = t; i < 128; i += 256)
      bs3[i] = (i < 100) ? (b3[i] + eb3[i]) : 0;
  }
}

// ---------------------------------------------------------------------------
// R7 gemm1: R6 pipeline UNCHANGED (3-stage LDS, depth-2 named-reg prefetch,
// counted vmcnt(10), raw barriers, 2 blk/CU) — ONLY the A global-load map
// changed. R6 diagnosis: per K-step = 6000 cyc with ~590 MFMA + ~600 VALU;
// the hole is transaction inflation: old map read 16 B/lane at 64 B stride
// (per instruction: 64 distinct lines, 25% used). pack_copy (R2) had the
// same pattern and capped at 30% of copy ceiling — the clean A/B.
// New A map: thread t -> rows (t>>4)+16j (j=0..7), chunk (t&15)*16 B of the
// row's 256 B step-slice. One wave-instruction = 4 rows x 256 B contiguous
// (16 fully-used lines, 4x fewer transactions). LDS image identical
// (row*80 + col*4 packed), so fragment reads + epilogue untouched.
// Per thread per step: 8 A + 2 B = 10 loads -> WAITV(10) math unchanged.
// ---------------------------------------------------------------------------
__global__ __launch_bounds__(256, 2) void gemm1_kernel(
    const int* __restrict__ X, const char* __restrict__ Btg,
    const int* __restrict__ bsum, const int* __restrict__ H,
    char* __restrict__ A8out) {
  constexpr int K = 3072, KIT = 48;
  __shared__ __align__(16) char smem[61440];
  const int t = threadIdx.x;
  const int bid = blockIdx.x;
  const int mt = bid & 63, nt = bid >> 6;
  const long m0 = (long)mt << 7;
  const int n0 = nt << 7;

  const int lane = t & 63, w = t >> 6;
  const int lc = lane & 31, hg = lane >> 5;
  const int wm = w >> 1, wn = w & 1;

  v16i acc[2][2] = {};

  // A staging (lane-contiguous): row (t>>4)+16j, 16 B chunk (t&15)*16.
  const int ar = t >> 4, ac = t & 15;
  const int* Xbase = X + (m0 + ar) * (long)K + ac * 4;
  const int awo = ar * 80 + ac * 4;
  // B staging (already lane-contiguous 64 B per row): unchanged from R6.
  const int r = t >> 2, q = t & 3;
  const char* Br0 = Btg + (long)(n0 + r) * K + q * 16;
  const char* Br1 = Br0 + (long)64 * K;
  const int bwo = 10240 + r * 80 + q * 16;

  // fragment read bases (80 B stride, chunk = ks*32 + hg*16)
  const int fa = (wm * 64 + lc) * 80;
  const int fb = 10240 + (wn * 64 + lc) * 80;

  int4 xA[8], yA[8], xB0, xB1, yB0, yB1;   // named depth-2 prefetch sets

  auto ISSUEX = [&](int kt) {
    const int ko = kt * 64;
    #pragma unroll
    for (int j = 0; j < 8; ++j)
      xA[j] = *(const int4*)(Xbase + (long)j * 16 * K + ko);
    xB0 = *(const int4*)(Br0 + ko);
    xB1 = *(const int4*)(Br1 + ko);
  };
  auto ISSUEY = [&](int kt) {
    const int ko = kt * 64;
    #pragma unroll
    for (int j = 0; j < 8; ++j)
      yA[j] = *(const int4*)(Xbase + (long)j * 16 * K + ko);
    yB0 = *(const int4*)(Br0 + ko);
    yB1 = *(const int4*)(Br1 + ko);
  };
  auto WRITEX = [&](int st) {
    char* base = smem + st * 20480;
    #pragma unroll
    for (int j = 0; j < 8; ++j)
      *(int*)(base + awo + j * 16 * 80) =
          pack4i(xA[j].x, xA[j].y, xA[j].z, xA[j].w);
    *(int4*)(base + bwo)           = xB0;
    *(int4*)(base + bwo + 64 * 80) = xB1;
  };
  auto WRITEY = [&](int st) {
    char* base = smem + st * 20480;
    #pragma unroll
    for (int j = 0; j < 8; ++j)
      *(int*)(base + awo + j * 16 * 80) =
          pack4i(yA[j].x, yA[j].y, yA[j].z, yA[j].w);
    *(int4*)(base + bwo)           = yB0;
    *(int4*)(base + bwo + 64 * 80) = yB1;
  };
  auto MSTEP = [&](int st) {
    const char* base = smem + st * 20480;
    __builtin_amdgcn_s_setprio(1);
    #pragma unroll
    for (int ks = 0; ks < 2; ++ks) {
      const int sel = ks * 32 + hg * 16;
      v4i a0 = *(const v4i*)(base + fa + sel);
      v4i a1 = *(const v4i*)(base + fa + 32 * 80 + sel);
      v4i b0 = *(const v4i*)(base + fb + sel);
      v4i b1 = *(const v4i*)(base + fb + 32 * 80 + sel);
      acc[0][0] = MFMA_I8(a0, b0, acc[0][0]);
      acc[0][1] = MFMA_I8(a0, b1, acc[0][1]);
      acc[1][0] = MFMA_I8(a1, b0, acc[1][0]);
      acc[1][1] = MFMA_I8(a1, b1, acc[1][1]);
    }
    __builtin_amdgcn_s_setprio(0);
  };

  ISSUEX(0);
  ISSUEY(1);
  WAITV(10);            // X-set landed (Y's 10 outstanding)
  WRITEX(0);
  BARX;
  for (int kt = 0; kt < KIT - 2; kt += 2) {
    ISSUEX(kt + 2);     // outstanding: Y(kt+1) 10 + X(kt+2) 10
    MSTEP(kt % 3);
    WAITV(10);          // Y(kt+1) landed; X stays in flight
    WRITEY((kt + 1) % 3);
    BARX;
    ISSUEY(kt + 3);
    MSTEP((kt + 1) % 3);
    WAITV(10);
    WRITEX((kt + 2) % 3);
    BARX;
  }
  MSTEP((KIT - 2) % 3);
  WAITV(0);
  WRITEY((KIT - 1) % 3);
  BARX;
  MSTEP((KIT - 1) % 3);

  // Epilogue (R5/R6-verified): LDS transpose stride 136 + SWAR-add trunc8(H).
  BARX;
  const int bsv0 = bsum[n0 + wn * 64 + lc];
  const int bsv1 = bsum[n0 + wn * 64 + 32 + lc];
  #pragma unroll
  for (int i = 0; i < 2; ++i) {
    #pragma unroll
    for (int j = 0; j < 2; ++j) {
      const int bv = j ? bsv1 : bsv0;
      const int col = wn * 64 + j * 32 + lc;
      #pragma unroll
      for (int rr = 0; rr < 16; ++rr) {
        const int row = wm * 64 + i * 32 + (hg << 2) + (rr & 3) + ((rr >> 2) << 3);
        smem[row * 136 + col] = (char)(acc[i][j][rr] + bv);
      }
    }
  }
  BARX;
  const char* srcp = smem + (t >> 1) * 136 + (t & 1) * 64;
  const long gco = (m0 + (t >> 1)) * 1024 + n0 + (t & 1) * 64;
  const int* hp = H + gco;
  #pragma unroll
  for (int g = 0; g < 4; ++g) {
    int4 s  = *(const int4*)(srcp + g * 16);
    int4 h0 = *(const int4*)(hp + g * 16);
    int4 h1 = *(const int4*)(hp + g * 16 + 4);
    int4 h2 = *(const int4*)(hp + g * 16 + 8);
    int4 h3 = *(const int4*)(hp + g * 16 + 12);
    s = make_int4(badd4(s.x, pack4i(h0.x, h0.y, h0.z, h0.w)),
                  badd4(s.y, pack4i(h1.x, h1.y, h1.z, h1.w)),
                  badd4(s.z, pack4i(h2.x, h2.y, h2.z, h2.w)),
                  badd4(s.w, pack4i(h3.x, h3.y, h3.z, h3.w)));
    *(int4*)(A8out + gco + g * 16) = s;
  }
}

// ---------------------------------------------------------------------------
// R6 gemm2 (unchanged): loads already lane-contiguous (int8: 4 lanes x 16 B
// = full 64 B line per row per instruction). Same pipeline, WAITV(4).
// ---------------------------------------------------------------------------
__global__ __launch_bounds__(256, 2) void gemm2_kernel(
    const char* __restrict__ A, const char* __restrict__ Btg,
    const int* __restrict__ bsum, int* __restrict__ Iout) {
  constexpr int K = 1024, KIT = 16;
  __shared__ __align__(16) char smem[61440];
  const int t = threadIdx.x;
  const int bid = blockIdx.x;
  const int mt = bid & 63, nt = bid >> 6;
  const long m0 = (long)mt << 7;
  const int n0 = nt << 7;

  const int lane = t & 63, w = t >> 6;
  const int lc = lane & 31, hg = lane >> 5;
  const int wm = w >> 1, wn = w & 1;

  v16i acc[2][2] = {};

  const int r = t >> 2, q = t & 3;
  const char* Ar0 = A + (m0 + r) * (long)K + q * 16;
  const char* Ar1 = Ar0 + (long)64 * K;
  const char* Br0 = Btg + (long)(n0 + r) * K + q * 16;
  const char* Br1 = Br0 + (long)64 * K;
  const int awo = r * 80 + q * 16;
  const int bwo = 10240 + r * 80 + q * 16;

  const int fa = (wm * 64 + lc) * 80;
  const int fb = 10240 + (wn * 64 + lc) * 80;

  int4 xA0, xA1, xB0, xB1, yA0, yA1, yB0, yB1;

  auto ISSUEX = [&](int kt) {
    const int ko = kt * 64;
    xA0 = *(const int4*)(Ar0 + ko);
    xA1 = *(const int4*)(Ar1 + ko);
    xB0 = *(const int4*)(Br0 + ko);
    xB1 = *(const int4*)(Br1 + ko);
  };
  auto ISSUEY = [&](int kt) {
    const int ko = kt * 64;
    yA0 = *(const int4*)(Ar0 + ko);
    yA1 = *(const int4*)(Ar1 + ko);
    yB0 = *(const int4*)(Br0 + ko);
    yB1 = *(const int4*)(Br1 + ko);
  };
  auto WRITEX = [&](int st) {
    char* base = smem + st * 20480;
    *(int4*)(base + awo)           = xA0;
    *(int4*)(base + awo + 64 * 80) = xA1;
    *(int4*)(base + bwo)           = xB0;
    *(int4*)(base + bwo + 64 * 80) = xB1;
  };
  auto WRITEY = [&](int st) {
    char* base = smem + st * 20480;
    *(int4*)(base + awo)           = yA0;
    *(int4*)(base + awo + 64 * 80) = yA1;
    *(int4*)(base + bwo)           = yB0;
    *(int4*)(base + bwo + 64 * 80) = yB1;
  };
  auto MSTEP = [&](int st) {
    const char* base = smem + st * 20480;
    __builtin_amdgcn_s_setprio(1);
    #pragma unroll
    for (int ks = 0; ks < 2; ++ks) {
      const int sel = ks * 32 + hg * 16;
      v4i a0 = *(const v4i*)(base + fa + sel);
      v4i a1 = *(const v4i*)(base + fa + 32 * 80 + sel);
      v4i b0 = *(const v4i*)(base + fb + sel);
      v4i b1 = *(const v4i*)(base + fb + 32 * 80 + sel);
      acc[0][0] = MFMA_I8(a0, b0, acc[0][0]);
      acc[0][1] = MFMA_I8(a0, b1, acc[0][1]);
      acc[1][0] = MFMA_I8(a1, b0, acc[1][0]);
      acc[1][1] = MFMA_I8(a1, b1, acc[1][1]);
    }
    __builtin_amdgcn_s_setprio(0);
  };

  ISSUEX(0);
  ISSUEY(1);
  WAITV(4);
  WRITEX(0);
  BARX;
  for (int kt = 0; kt < KIT - 2; kt += 2) {
    ISSUEX(kt + 2);
    MSTEP(kt % 3);
    WAITV(4);
    WRITEY((kt + 1) % 3);
    BARX;
    ISSUEY(kt + 3);
    MSTEP((kt + 1) % 3);
    WAITV(4);
    WRITEX((kt + 2) % 3);
    BARX;
  }
  MSTEP((KIT - 2) % 3);
  WAITV(0);
  WRITEY((KIT - 1) % 3);
  BARX;
  MSTEP((KIT - 1) % 3);

  const int bsj0 = bsum[n0 + wn * 64 + lc];
  const int bsj1 = bsum[n0 + wn * 64 + 32 + lc];
  #pragma unroll
  for (int i = 0; i < 2; ++i) {
    #pragma unroll
    for (int j = 0; j < 2; ++j) {
      const int bv = j ? bsj1 : bsj0;
      const int col = n0 + wn * 64 + j * 32 + lc;
      #pragma unroll
      for (int rr = 0; rr < 16; ++rr) {
        const long row = m0 + wm * 64 + i * 32 + (hg << 2) + (rr & 3) + ((rr >> 2) << 3);
        Iout[row * 1024 + col] = (int)(signed char)(acc[i][j][rr] + bv);
      }
    }
  }
}

// ---------------------------------------------------------------------------
// Layer 3: 16x128 tile, 512 blocks (2/CU), mfma_i32_16x16x64_i8, 2-stage.
// A = h2 int32 from d_out, packed to int8 in staging. (Long-verified.)
// ---------------------------------------------------------------------------
__global__ __launch_bounds__(256, 2) void gemm3_kernel(
    const int* __restrict__ h2, const char* __restrict__ Btg,
    const int* __restrict__ bsum, int* __restrict__ Iout) {
  // stage: As 16x80 (1280) + Bs 128x80 (10240) = 11520; x2 = 23040
  __shared__ __align__(16) char smem[23040];
  const int t = threadIdx.x;
  const int m0 = blockIdx.x << 4;
  const int lane = t & 63, w = t >> 6;
  const int l16 = lane & 15, q = lane >> 4;
  v4i acc0 = {}, acc1 = {};

  const int am = t >> 4, ah = t & 15;      // 16 rows x 16 thr x 4 ints
  const int* Arow = h2 + (long)(m0 + am) * 1024 + ah * 4;
  const int aoff = am * 80 + ah * 4;
  const int bm = t >> 1, bh = t & 1;       // 128 rows x 2 thr x 32 B
  const char* Brow = Btg + (long)bm * 1024 + bh * 32;
  const int boff = bm * 80 + bh * 32;

  const int abo  = l16 * 80 + q * 16;
  const int bbo0 = (w * 32 + l16) * 80 + q * 16;
  const int bbo1 = (w * 32 + 16 + l16) * 80 + q * 16;

  int4 ar, br0, br1;
  auto LOAD = [&](int kt) {
    const int kb = kt << 6;
    ar  = *(const int4*)(Arow + kb);
    br0 = *(const int4*)(Brow + kb);
    br1 = *(const int4*)(Brow + kb + 16);
  };
  auto STORE = [&](int stage) {
    char* base = smem + stage * 11520;
    *(int*)(base + aoff) = pack4i(ar.x, ar.y, ar.z, ar.w);
    *(int4*)(base + 1280 + boff)      = br0;
    *(int4*)(base + 1280 + boff + 16) = br1;
  };
  auto MFMA = [&](int stage) {
    const char* base = smem + stage * 11520;
    v4i a  = *(const v4i*)(base + abo);
    v4i b0 = *(const v4i*)(base + 1280 + bbo0);
    v4i b1 = *(const v4i*)(base + 1280 + bbo1);
    acc0 = __builtin_amdgcn_mfma_i32_16x16x64_i8(a, b0, acc0, 0, 0, 0);
    acc1 = __builtin_amdgcn_mfma_i32_16x16x64_i8(a, b1, acc1, 0, 0, 0);
  };

  LOAD(0); STORE(0); __syncthreads();
  for (int kt = 0; kt < 16; ++kt) {
    if (kt + 1 < 16) LOAD(kt + 1);
    MFMA(kt & 1);
    if (kt + 1 < 16) { STORE((kt + 1) & 1); __syncthreads(); }
  }

  const int c0 = w * 32 + l16;       // cols {0-15,32-47,64-79,96-111}
  const int c1 = c0 + 16;            // cols {16-31,48-63,80-95,112-127}
  if (c0 < 100) {
    const int b = bsum[c0];
    #pragma unroll
    for (int rr = 0; rr < 4; ++rr)
      Iout[(long)(m0 + q * 4 + rr) * 100 + c0] = (int)(signed char)(acc0[rr] + b);
  }
  if (c1 < 100) {
    const int b = bsum[c1];
    #pragma unroll
    for (int rr = 0; rr < 4; ++rr)
      Iout[(long)(m0 + q * 4 + rr) * 100 + c1] = (int)(signed char)(acc1[rr] + b);
  }
}

// ---------------------------------------------------------------------------
// ws (12.7 MB): Bt1 | Bt2 | Bt3 | bs1 | bs2 | bs3 | A2
// ---------------------------------------------------------------------------
extern "C" void kernel_launch(void* const* d_in, const int* in_sizes, int n_in,
                              void* d_out, int out_size, void* d_ws, size_t ws_size,
                              hipStream_t stream) {
  (void)in_sizes; (void)n_in; (void)out_size; (void)ws_size;
  const int* W1  = (const int*)d_in[0];
  const int* b1  = (const int*)d_in[1];
  const int* W2  = (const int*)d_in[2];
  const int* b2  = (const int*)d_in[3];
  const int* W3  = (const int*)d_in[4];
  const int* b3  = (const int*)d_in[5];
  const int* E1  = (const int*)d_in[6];
  const int* eb1 = (const int*)d_in[7];
  const int* E2  = (const int*)d_in[8];
  const int* eb2 = (const int*)d_in[9];
  const int* E3  = (const int*)d_in[10];
  const int* eb3 = (const int*)d_in[11];
  const int* X   = (const int*)d_in[12];   // [8192][3072] int32
  const int* H   = (const int*)d_in[13];   // [8192][1024] int32
  int* out = (int*)d_out;                  // h2 [8192*1024] then out [8192*100]

  char* ws  = (char*)d_ws;
  char* Bt1 = ws;                          // 3,145,728
  char* Bt2 = Bt1 + 3145728;               // 1,048,576
  char* Bt3 = Bt2 + 1048576;               //   131,072 (rows 100..127 zeroed)
  int*  bs1 = (int*)(Bt3 + 131072);        // 1024 ints
  int*  bs2 = bs1 + 1024;                  // 1024 ints
  int*  bs3 = bs2 + 1024;                  //  128 ints
  char* A2  = (char*)(bs3 + 128);          // 8,388,608 int8

  pack_weights_kernel<<<dim3(265), dim3(256), 0, stream>>>(
      W1, E1, Bt1, W2, E2, Bt2, W3, E3, Bt3,
      b1, eb1, bs1, b2, eb2, bs2, b3, eb3, bs3);

  // Layer 1: X (int32, fused pack) -> i2c ; epilogue adds trunc8(H) -> A2
  gemm1_kernel<<<dim3(512), dim3(256), 0, stream>>>(X, Bt1, bs1, H, A2);

  // Layer 2: h2 -> d_out (int32)
  gemm2_kernel<<<dim3(512), dim3(256), 0, stream>>>(A2, Bt2, bs2, out);

  // Layer 3: reads h2 from d_out (int32), writes out region (int32)
  gemm3_kernel<<<dim3(512), dim3(256), 0, stream>>>(
      out, Bt3, bs3, out + 8388608);
}